// Round 1
// baseline (624.726 us; speedup 1.0000x reference)
//
#include <hip/hip_runtime.h>

constexpr int NENV  = 4096;
constexpr int NA    = 32;    // agents/env
constexpr int IND   = 32;    // IN_DIM
constexpr int GD    = 64;    // GCN_DIM
constexpr int RD3   = 192;   // 3*RNN_DIM
constexpr int EPER  = 256;
constexpr int NNODES = NENV * NA;

// ---------------- K0: fold W_pre@W_gcn, b_pre@W_gcn; zero edge-dtype flag --------
__global__ __launch_bounds__(256) void prep_kernel(
    const float* __restrict__ W_pre, const float* __restrict__ b_pre,
    const float* __restrict__ W_gcn, float* __restrict__ Wc,
    float* __restrict__ bc, int* __restrict__ flag)
{
    int t = threadIdx.x;
    if (t == 0) *flag = 0;
    for (int o = t; o < IND * GD; o += 256) {
        int k = o >> 6, d = o & 63;
        float s = 0.f;
        for (int m = 0; m < GD; ++m) s += W_pre[k * GD + m] * W_gcn[m * GD + d];
        Wc[o] = s;
    }
    if (t < GD) {
        float s = 0.f;
        for (int m = 0; m < GD; ++m) s += b_pre[m] * W_gcn[m * GD + t];
        bc[t] = s;
    }
}

// ---------------- K0b: detect edge dtype (int64 -> all odd 32-bit words are 0) ---
__global__ __launch_bounds__(256) void detect_kernel(const int* __restrict__ e32,
                                                     int* __restrict__ flag)
{
    int i = blockIdx.x * 256 + threadIdx.x;          // 0..262143
    int v = 0;
    #pragma unroll
    for (int j = 0; j < 4; ++j) v |= e32[2 * (i + j * 262144) + 1];
    if (__any(v != 0) && (threadIdx.x & 63) == 0) atomicOr(flag, 1);
}

// ---------------- K1: per-env GCN: h = x@Wc+bc ; deg ; normalized scatter-add ----
__global__ __launch_bounds__(256) void gcn_kernel(
    const float* __restrict__ x,      // [4096][32][32]
    const void*  __restrict__ edge,   // [4096][2][256] int32 or int64
    const float* __restrict__ Wc,     // [32][64]
    const float* __restrict__ bc,     // [64]
    const float* __restrict__ b_gcn,  // [64]
    const int*   __restrict__ flag,   // 0 => int64 edges
    float* __restrict__ agg_out)      // [N][64]
{
    __shared__ float sx[NA][36];
    __shared__ float sWc[IND][GD];
    __shared__ float sh[NA][GD + 4];
    __shared__ float sagg[NA][GD + 4];
    __shared__ int   srow[EPER], scol[EPER];
    __shared__ int   sdeg[NA];
    __shared__ float sdinv[NA];
    __shared__ float sbc[GD], sbg[GD];

    const int env = blockIdx.x;
    const int t   = threadIdx.x;

    {
        const float4* x4 = (const float4*)(x + (size_t)env * NA * IND);
        float4 v = x4[t];
        int row = t >> 3, c4 = t & 7;
        ((float4*)&sx[row][0])[c4] = v;
    }
    {
        const float4* w4 = (const float4*)Wc;
        ((float4*)&sWc[0][0])[t]       = w4[t];
        ((float4*)&sWc[0][0])[t + 256] = w4[t + 256];
    }
    if (t < GD) { sbc[t] = bc[t]; sbg[t] = b_gcn[t]; }
    {
        const int is32 = *flag;
        if (is32) {
            const int* ep = (const int*)edge + (size_t)env * 2 * EPER;
            srow[t] = ep[t]; scol[t] = ep[EPER + t];
        } else {
            const long long* ep = (const long long*)edge + (size_t)env * 2 * EPER;
            srow[t] = (int)ep[t]; scol[t] = (int)ep[EPER + t];
        }
    }
    if (t < NA) sdeg[t] = 1;
    __syncthreads();

    atomicAdd(&sdeg[scol[t]], 1);
    __syncthreads();
    if (t < NA) sdinv[t] = rsqrtf((float)sdeg[t]);

    {
        const int n0 = (t >> 4) << 1;
        const int dt = t & 15;
        float a0x = 0.f, a0y = 0.f, a0z = 0.f, a0w = 0.f;
        float a1x = 0.f, a1y = 0.f, a1z = 0.f, a1w = 0.f;
        #pragma unroll
        for (int k = 0; k < IND; ++k) {
            float4 w = ((const float4*)&sWc[k][0])[dt];
            float v0 = sx[n0][k], v1 = sx[n0 + 1][k];
            a0x += v0 * w.x; a0y += v0 * w.y; a0z += v0 * w.z; a0w += v0 * w.w;
            a1x += v1 * w.x; a1y += v1 * w.y; a1z += v1 * w.z; a1w += v1 * w.w;
        }
        int d0 = dt << 2;
        float4 b = *(const float4*)&sbc[d0];
        float4 r0 = {a0x + b.x, a0y + b.y, a0z + b.z, a0w + b.w};
        float4 r1 = {a1x + b.x, a1y + b.y, a1z + b.z, a1w + b.w};
        *(float4*)&sh[n0][d0]     = r0;
        *(float4*)&sh[n0 + 1][d0] = r1;
    }
    __syncthreads();

    #pragma unroll
    for (int i = 0; i < 8; ++i) {
        int o = t + (i << 8);
        int n = o >> 6, d = o & 63;
        float di = sdinv[n];
        sagg[n][d] = sh[n][d] * di * di + sbg[d];
    }
    __syncthreads();

    {
        const int d = t & 63;
        const int esub = t >> 6;
        for (int i = 0; i < EPER / 4; ++i) {
            int e = (i << 2) + esub;
            int r = srow[e], c = scol[e];
            float w = sdinv[r] * sdinv[c];
            atomicAdd(&sagg[c][d], sh[r][d] * w);
        }
    }
    __syncthreads();

    float* ao = agg_out + (size_t)env * NA * GD;
    #pragma unroll
    for (int i = 0; i < 8; ++i) {
        int o = t + (i << 8);
        ao[o] = sagg[o >> 6][o & 63];
    }
}

// ---------------- K2: GRU + value head, 64 nodes (2 envs) per block --------------
__global__ __launch_bounds__(256) void gru_kernel(
    const float* __restrict__ agg_in,
    const float* __restrict__ h0,
    const float* __restrict__ W_ih,
    const float* __restrict__ W_hh,
    const float* __restrict__ b_ih, const float* __restrict__ b_hh,
    const float* __restrict__ W_out,
    const float* __restrict__ b_out,
    float* __restrict__ value,
    float* __restrict__ hid_out)
{
    __shared__ float s_act[64][68];
    __shared__ float s_h0[64][68];
    __shared__ float s_bih[RD3], s_bhh[RD3];
    __shared__ float s_red[4];

    const int t = threadIdx.x;
    const size_t nb0 = (size_t)blockIdx.x * 64;

    {
        const float4* a4 = (const float4*)(agg_in + nb0 * GD);
        const float4* h4 = (const float4*)(h0 + nb0 * GD);
        #pragma unroll
        for (int i = 0; i < 4; ++i) {
            int idx = t + (i << 8);
            int n = idx >> 4, kk = idx & 15;
            ((float4*)&s_act[n][0])[kk] = a4[idx];
            ((float4*)&s_h0[n][0])[kk]  = h4[idx];
        }
    }
    if (t < RD3) { s_bih[t] = b_ih[t]; s_bhh[t] = b_hh[t]; }
    __syncthreads();

    const int nt = t >> 5;
    const int n0 = nt << 3;
    const int gt = t & 31;
    const int a0 = gt << 1;

    float acc_i[8][6], acc_h[8][6];
    #pragma unroll
    for (int a = 0; a < 8; ++a)
        #pragma unroll
        for (int b = 0; b < 6; ++b) { acc_i[a][b] = 0.f; acc_h[a][b] = 0.f; }

    #pragma unroll 2
    for (int k4 = 0; k4 < 16; ++k4) {
        float4 w[6];
        #pragma unroll
        for (int g3 = 0; g3 < 3; ++g3)
            #pragma unroll
            for (int jj = 0; jj < 2; ++jj)
                w[g3 * 2 + jj] = ((const float4*)(W_ih + (size_t)(g3 * 64 + a0 + jj) * GD))[k4];
        #pragma unroll
        for (int nn = 0; nn < 8; ++nn) {
            float4 a = ((const float4*)&s_act[n0 + nn][0])[k4];
            #pragma unroll
            for (int b = 0; b < 6; ++b)
                acc_i[nn][b] += a.x * w[b].x + a.y * w[b].y + a.z * w[b].z + a.w * w[b].w;
        }
    }
    #pragma unroll 2
    for (int k4 = 0; k4 < 16; ++k4) {
        float4 w[6];
        #pragma unroll
        for (int g3 = 0; g3 < 3; ++g3)
            #pragma unroll
            for (int jj = 0; jj < 2; ++jj)
                w[g3 * 2 + jj] = ((const float4*)(W_hh + (size_t)(g3 * 64 + a0 + jj) * GD))[k4];
        #pragma unroll
        for (int nn = 0; nn < 8; ++nn) {
            float4 a = ((const float4*)&s_h0[n0 + nn][0])[k4];
            #pragma unroll
            for (int b = 0; b < 6; ++b)
                acc_h[nn][b] += a.x * w[b].x + a.y * w[b].y + a.z * w[b].z + a.w * w[b].w;
        }
    }

    __syncthreads();
    float* s_hnew = &s_act[0][0];
    #pragma unroll
    for (int nn = 0; nn < 8; ++nn) {
        #pragma unroll
        for (int jj = 0; jj < 2; ++jj) {
            int d = a0 + jj;
            float sr = (acc_i[nn][0 + jj] + s_bih[d])      + (acc_h[nn][0 + jj] + s_bhh[d]);
            float sz = (acc_i[nn][2 + jj] + s_bih[64 + d]) + (acc_h[nn][2 + jj] + s_bhh[64 + d]);
            float in_ = acc_i[nn][4 + jj] + s_bih[128 + d];
            float hn  = acc_h[nn][4 + jj] + s_bhh[128 + d];
            float r = 1.f / (1.f + __expf(-sr));
            float z = 1.f / (1.f + __expf(-sz));
            float e2 = __expf(2.f * (in_ + r * hn));
            float nv = 1.f - 2.f / (e2 + 1.f);
            float h0v = s_h0[n0 + nn][d];
            s_hnew[(n0 + nn) * 68 + d] = (1.f - z) * nv + z * h0v;
        }
    }
    __syncthreads();

    float* ho = hid_out + nb0 * GD;
    #pragma unroll
    for (int i = 0; i < 16; ++i) {
        int o = t + (i << 8);
        ho[o] = s_hnew[(o >> 6) * 68 + (o & 63)];
    }

    float vsum = 0.f;
    {
        const int half = t >> 7, lt = t & 127;
        #pragma unroll
        for (int i = 0; i < 16; ++i) {
            int idx = lt + (i << 7);
            int n = (idx >> 6) + half * 32;
            vsum += s_hnew[n * 68 + (idx & 63)] * W_out[idx];
        }
    }
    #pragma unroll
    for (int off = 32; off > 0; off >>= 1) vsum += __shfl_down(vsum, off, 64);
    if ((t & 63) == 0) s_red[t >> 6] = vsum;
    __syncthreads();
    if (t == 0)   value[blockIdx.x * 2]     = s_red[0] + s_red[1] + b_out[0];
    if (t == 128) value[blockIdx.x * 2 + 1] = s_red[2] + s_red[3] + b_out[0];
}

// ---------------------------------------------------------------------------------
extern "C" void kernel_launch(void* const* d_in, const int* in_sizes, int n_in,
                              void* d_out, int out_size, void* d_ws, size_t ws_size,
                              hipStream_t stream)
{
    const float* x     = (const float*)d_in[0];
    const void*  edge  = d_in[1];
    const float* h0    = (const float*)d_in[2];
    const float* W_pre = (const float*)d_in[3];
    const float* b_pre = (const float*)d_in[4];
    const float* W_gcn = (const float*)d_in[5];
    const float* b_gcn = (const float*)d_in[6];
    const float* W_ih  = (const float*)d_in[7];
    const float* W_hh  = (const float*)d_in[8];
    const float* b_ih  = (const float*)d_in[9];
    const float* b_hh  = (const float*)d_in[10];
    const float* W_out = (const float*)d_in[11];
    const float* b_out = (const float*)d_in[12];

    float* value = (float*)d_out;
    float* hid   = (float*)d_out + NENV;   // agg scratch, finally next_hidden

    float* Wc   = (float*)d_ws;
    float* bc   = Wc + IND * GD;
    int*   flag = (int*)(bc + GD);

    prep_kernel<<<1, 256, 0, stream>>>(W_pre, b_pre, W_gcn, Wc, bc, flag);
    detect_kernel<<<1024, 256, 0, stream>>>((const int*)edge, flag);
    gcn_kernel<<<NENV, 256, 0, stream>>>(x, edge, Wc, bc, b_gcn, flag, hid);
    gru_kernel<<<NNODES / 64, 256, 0, stream>>>(hid, h0, W_ih, W_hh, b_ih, b_hh,
                                                W_out, b_out, value, hid);
}

// Round 2
// 150.580 us; speedup vs baseline: 4.1488x; 4.1488x over previous
//
#include <hip/hip_runtime.h>

constexpr int NENV  = 4096;
constexpr int NA    = 32;    // agents/env
constexpr int IND   = 32;    // IN_DIM
constexpr int GD    = 64;    // GCN_DIM
constexpr int RD3   = 192;   // 3*RNN_DIM
constexpr int EPER  = 256;
constexpr int NNODES = NENV * NA;

typedef __attribute__((ext_vector_type(8))) short bf16x8;
typedef __attribute__((ext_vector_type(4))) float f32x4;

__device__ __forceinline__ unsigned short f2bf(float f) {
    unsigned u = __float_as_uint(f);
    u += 0x7FFFu + ((u >> 16) & 1u);          // round-to-nearest-even
    return (unsigned short)(u >> 16);
}

__device__ __forceinline__ bf16x8 ldcvt8(const float* p) {
    f32x4 a = *(const f32x4*)p;
    f32x4 b = *(const f32x4*)(p + 4);
    bf16x8 r;
    r[0] = (short)f2bf(a[0]); r[1] = (short)f2bf(a[1]);
    r[2] = (short)f2bf(a[2]); r[3] = (short)f2bf(a[3]);
    r[4] = (short)f2bf(b[0]); r[5] = (short)f2bf(b[1]);
    r[6] = (short)f2bf(b[2]); r[7] = (short)f2bf(b[3]);
    return r;
}

// ---- K0: blocks 0..95 convert W_ih/W_hh -> bf16; block 96 folds Wc/bc, zeroes flag
__global__ __launch_bounds__(256) void prep_kernel(
    const float* __restrict__ W_pre, const float* __restrict__ b_pre,
    const float* __restrict__ W_gcn,
    const float* __restrict__ W_ih,  const float* __restrict__ W_hh,
    float* __restrict__ Wc, float* __restrict__ bc, int* __restrict__ flag,
    short* __restrict__ WihB, short* __restrict__ WhhB)
{
    int b = blockIdx.x, t = threadIdx.x;
    if (b == 96) {
        if (t == 0) *flag = 0;
        for (int o = t; o < IND * GD; o += 256) {
            int k = o >> 6, d = o & 63;
            float s = 0.f;
            for (int m = 0; m < GD; ++m) s += W_pre[k * GD + m] * W_gcn[m * GD + d];
            Wc[o] = s;
        }
        if (t < GD) {
            float s = 0.f;
            for (int m = 0; m < GD; ++m) s += b_pre[m] * W_gcn[m * GD + t];
            bc[t] = s;
        }
    } else {
        int i = b * 256 + t;                  // 0..24575
        if (i < RD3 * GD) WihB[i] = (short)f2bf(W_ih[i]);
        else              WhhB[i - RD3 * GD] = (short)f2bf(W_hh[i - RD3 * GD]);
    }
}

// ---- K0b: detect edge dtype (int64 -> all odd 32-bit words are 0)
__global__ __launch_bounds__(256) void detect_kernel(const int* __restrict__ e32,
                                                     int* __restrict__ flag)
{
    int i = blockIdx.x * 256 + threadIdx.x;   // 0..262143
    int v = 0;
    #pragma unroll
    for (int j = 0; j < 4; ++j) v |= e32[2 * (i + j * 262144) + 1];
    if (__any(v != 0) && (threadIdx.x & 63) == 0) atomicOr(flag, 1);
}

// ---- K1: per-env GCN via dense normalized adjacency + two small GEMMs ----------
__global__ __launch_bounds__(256) void gcn_kernel(
    const float* __restrict__ x,      // [4096][32][32]
    const void*  __restrict__ edge,   // [4096][2][256] int32 or int64
    const float* __restrict__ Wc,     // [32][64]
    const float* __restrict__ bc,     // [64]
    const float* __restrict__ b_gcn,  // [64]
    const int*   __restrict__ flag,   // 0 => int64 edges
    float* __restrict__ agg_out)      // [N][64] f32
{
    __shared__ float sx[NA][36];
    __shared__ float sWc[IND][GD];
    __shared__ float sh[NA][GD + 4];
    __shared__ float sA[NA][NA + 1];
    __shared__ int   srow[EPER], scol[EPER];
    __shared__ int   sdeg[NA];
    __shared__ float sdinv[NA];
    __shared__ float sbc[GD], sbg[GD];

    const int env = blockIdx.x;
    const int t   = threadIdx.x;

    // ---------- phase 1: stage everything, init counters ----------
    {
        f32x4 v = ((const f32x4*)(x + (size_t)env * NA * IND))[t];
        ((f32x4*)&sx[t >> 3][0])[t & 7] = v;
    }
    {
        const f32x4* w4 = (const f32x4*)Wc;
        ((f32x4*)&sWc[0][0])[t]       = w4[t];
        ((f32x4*)&sWc[0][0])[t + 256] = w4[t + 256];
    }
    if (t < GD) { sbc[t] = bc[t]; sbg[t] = b_gcn[t]; }
    {
        const int is32 = *flag;
        if (is32) {
            const int* ep = (const int*)edge + (size_t)env * 2 * EPER;
            srow[t] = ep[t]; scol[t] = ep[EPER + t];
        } else {
            const long long* ep = (const long long*)edge + (size_t)env * 2 * EPER;
            srow[t] = (int)ep[t]; scol[t] = (int)ep[EPER + t];
        }
    }
    if (t < NA) sdeg[t] = 1;                  // self loop
    #pragma unroll
    for (int i = 0; i < 5; ++i) {             // zero sA (1056 floats)
        int o = t + (i << 8);
        if (o < NA * (NA + 1)) (&sA[0][0])[o] = 0.f;
    }
    __syncthreads();

    // ---------- phase 2: degree + adjacency counts + GEMM1 ----------
    atomicAdd(&sdeg[scol[t]], 1);
    atomicAdd(&sA[scol[t]][srow[t]], 1.0f);
    {
        const int n0 = (t >> 4) << 1;
        const int dt = t & 15;
        f32x4 a0 = {0.f, 0.f, 0.f, 0.f}, a1 = {0.f, 0.f, 0.f, 0.f};
        #pragma unroll
        for (int k = 0; k < IND; ++k) {
            f32x4 w = ((const f32x4*)&sWc[k][0])[dt];
            a0 += sx[n0][k] * w;
            a1 += sx[n0 + 1][k] * w;
        }
        int d0 = dt << 2;
        f32x4 b = *(const f32x4*)&sbc[d0];
        *(f32x4*)&sh[n0][d0]     = a0 + b;
        *(f32x4*)&sh[n0 + 1][d0] = a1 + b;
    }
    __syncthreads();

    // ---------- phase 3: dinv ----------
    if (t < NA) sdinv[t] = rsqrtf((float)sdeg[t]);
    __syncthreads();

    // ---------- phase 4: normalize adjacency (+ self-loop diagonal) ----------
    #pragma unroll
    for (int i = 0; i < 4; ++i) {
        int o = t + (i << 8);                 // 0..1023
        int c = o >> 5, r = o & 31;
        float v = sA[c][r] * sdinv[c] * sdinv[r];
        if (r == c) v += sdinv[c] * sdinv[c];
        sA[c][r] = v;
    }
    __syncthreads();

    // ---------- phase 5: gather GEMM agg = A_hat @ h + b_gcn ----------
    {
        const int c0 = (t >> 4) << 1;
        const int dt = t & 15;
        f32x4 a0 = {0.f, 0.f, 0.f, 0.f}, a1 = {0.f, 0.f, 0.f, 0.f};
        #pragma unroll
        for (int r = 0; r < NA; ++r) {
            f32x4 hv = ((const f32x4*)&sh[r][0])[dt];
            a0 += sA[c0][r]     * hv;
            a1 += sA[c0 + 1][r] * hv;
        }
        int d0 = dt << 2;
        f32x4 bg = {sbg[d0], sbg[d0 + 1], sbg[d0 + 2], sbg[d0 + 3]};
        float* ao = agg_out + (size_t)env * NA * GD;
        *(f32x4*)&ao[c0 * GD + d0]       = a0 + bg;
        *(f32x4*)&ao[(c0 + 1) * GD + d0] = a1 + bg;
    }
}

// ---- K2: GRU via bf16 MFMA + fused value head. 64 nodes (2 envs) / block -------
__global__ __launch_bounds__(256) void gru_kernel(
    const float* __restrict__ agg,    // [N][64] f32 (aliases hid_out)
    const float* __restrict__ h0f,    // [N][64] f32
    const short* __restrict__ WihB,   // [192][64] bf16
    const short* __restrict__ WhhB,   // [192][64] bf16
    const float* __restrict__ b_ih, const float* __restrict__ b_hh,
    const float* __restrict__ W_out,  // [2048]
    const float* __restrict__ b_out,
    float* __restrict__ value,        // [4096]
    float* __restrict__ hid_out)      // [N][64]
{
    __shared__ float s_hnew[64 * 65];
    __shared__ float s_bih[RD3], s_bhh[RD3];
    __shared__ float s_red[4];

    const int t   = threadIdx.x;
    const int w   = t >> 6;          // wave 0..3 -> owns gate-dims [16w,16w+16)
    const int l   = t & 63;
    const int col = l & 15;          // node-within-tile / W-row-within-tile
    const int lg  = l >> 4;          // 0..3
    const size_t nb = (size_t)blockIdx.x * 64;

    if (t < RD3) { s_bih[t] = b_ih[t]; s_bhh[t] = b_hh[t]; }

    f32x4 acc_i[3][4] = {};          // [gate r,z,n][node-tile]
    f32x4 acc_h[3][4] = {};

    #pragma unroll
    for (int kt = 0; kt < 2; ++kt) {
        bf16x8 Ba[4], Bh[4];
        #pragma unroll
        for (int nt = 0; nt < 4; ++nt) {
            size_t off = (nb + nt * 16 + col) * GD + kt * 32 + lg * 8;
            Ba[nt] = ldcvt8(agg + off);
            Bh[nt] = ldcvt8(h0f + off);
        }
        #pragma unroll
        for (int g = 0; g < 3; ++g) {
            int wrow = g * 64 + 16 * w + col;
            bf16x8 Ai = *(const bf16x8*)(WihB + wrow * GD + kt * 32 + lg * 8);
            bf16x8 Ah = *(const bf16x8*)(WhhB + wrow * GD + kt * 32 + lg * 8);
            #pragma unroll
            for (int nt = 0; nt < 4; ++nt) {
                acc_i[g][nt] = __builtin_amdgcn_mfma_f32_16x16x32_bf16(Ai, Ba[nt], acc_i[g][nt], 0, 0, 0);
                acc_h[g][nt] = __builtin_amdgcn_mfma_f32_16x16x32_bf16(Ah, Bh[nt], acc_h[g][nt], 0, 0, 0);
            }
        }
    }
    __syncthreads();                 // biases staged; LDS not yet touched otherwise

    // epilogue: thread holds matched (r,z,n) triples at (node, d)
    const int dbase = 16 * w + 4 * lg;
    #pragma unroll
    for (int nt = 0; nt < 4; ++nt) {
        int node = nt * 16 + col;
        f32x4 h0v = *(const f32x4*)(h0f + (nb + node) * GD + dbase);
        #pragma unroll
        for (int r_ = 0; r_ < 4; ++r_) {
            int d = dbase + r_;
            float gir = acc_i[0][nt][r_] + s_bih[d];
            float giz = acc_i[1][nt][r_] + s_bih[64 + d];
            float gin = acc_i[2][nt][r_] + s_bih[128 + d];
            float ghr = acc_h[0][nt][r_] + s_bhh[d];
            float ghz = acc_h[1][nt][r_] + s_bhh[64 + d];
            float ghn = acc_h[2][nt][r_] + s_bhh[128 + d];
            float rr = 1.f / (1.f + __expf(-(gir + ghr)));
            float zz = 1.f / (1.f + __expf(-(giz + ghz)));
            float e2 = __expf(2.f * (gin + rr * ghn));
            float nn = 1.f - 2.f / (e2 + 1.f);       // tanh, inf-safe
            s_hnew[node * 65 + d] = (1.f - zz) * nn + zz * h0v[r_];
        }
    }
    __syncthreads();

    // coalesced hnew flush
    float* ho = hid_out + nb * GD;
    #pragma unroll
    for (int i = 0; i < 16; ++i) {
        int o = t + (i << 8);
        ho[o] = s_hnew[(o >> 6) * 65 + (o & 63)];
    }

    // value head: half-block per env
    float vsum = 0.f;
    {
        const int half = t >> 7, lt = t & 127;
        #pragma unroll
        for (int i = 0; i < 16; ++i) {
            int idx = lt + (i << 7);            // 0..2047 = agent*64 + d
            int n = (idx >> 6) + half * 32;
            vsum += s_hnew[n * 65 + (idx & 63)] * W_out[idx];
        }
    }
    #pragma unroll
    for (int off = 32; off > 0; off >>= 1) vsum += __shfl_down(vsum, off, 64);
    if ((t & 63) == 0) s_red[t >> 6] = vsum;
    __syncthreads();
    if (t == 0)   value[blockIdx.x * 2]     = s_red[0] + s_red[1] + b_out[0];
    if (t == 128) value[blockIdx.x * 2 + 1] = s_red[2] + s_red[3] + b_out[0];
}

// ---------------------------------------------------------------------------------
extern "C" void kernel_launch(void* const* d_in, const int* in_sizes, int n_in,
                              void* d_out, int out_size, void* d_ws, size_t ws_size,
                              hipStream_t stream)
{
    const float* x     = (const float*)d_in[0];
    const void*  edge  = d_in[1];
    const float* h0    = (const float*)d_in[2];
    const float* W_pre = (const float*)d_in[3];
    const float* b_pre = (const float*)d_in[4];
    const float* W_gcn = (const float*)d_in[5];
    const float* b_gcn = (const float*)d_in[6];
    const float* W_ih  = (const float*)d_in[7];
    const float* W_hh  = (const float*)d_in[8];
    const float* b_ih  = (const float*)d_in[9];
    const float* b_hh  = (const float*)d_in[10];
    const float* W_out = (const float*)d_in[11];
    const float* b_out = (const float*)d_in[12];

    float* value = (float*)d_out;
    float* hid   = (float*)d_out + NENV;        // agg scratch, finally next_hidden

    float* Wc   = (float*)d_ws;                 // 2048 f32
    float* bc   = Wc + IND * GD;                // 64 f32
    int*   flag = (int*)(bc + GD);
    short* WihB = (short*)((char*)d_ws + 9216); // 12288 bf16
    short* WhhB = WihB + RD3 * GD;              // 12288 bf16

    prep_kernel<<<97, 256, 0, stream>>>(W_pre, b_pre, W_gcn, W_ih, W_hh,
                                        Wc, bc, flag, WihB, WhhB);
    detect_kernel<<<1024, 256, 0, stream>>>((const int*)edge, flag);
    gcn_kernel<<<NENV, 256, 0, stream>>>(x, edge, Wc, bc, b_gcn, flag, hid);
    gru_kernel<<<NNODES / 64, 256, 0, stream>>>(hid, h0, WihB, WhhB, b_ih, b_hh,
                                                W_out, b_out, value, hid);
}

// Round 3
// 65.832 us; speedup vs baseline: 9.4897x; 2.2873x over previous
//
#include <hip/hip_runtime.h>

constexpr int NENV  = 4096;
constexpr int NA    = 32;
constexpr int IND   = 32;
constexpr int GD    = 64;
constexpr int RD3   = 192;

typedef __attribute__((ext_vector_type(8))) short s16x8;
typedef __attribute__((ext_vector_type(4))) short s16x4;
typedef __attribute__((ext_vector_type(4))) float f32x4;

__device__ __forceinline__ unsigned short f2bf(float f) {
    unsigned u = __float_as_uint(f);
    u += 0x7FFFu + ((u >> 16) & 1u);
    return (unsigned short)(u >> 16);
}
__device__ __forceinline__ float bf2f(unsigned short u) {
    return __uint_as_float((unsigned)u << 16);
}
__device__ __forceinline__ s16x8 cvt8(const float* p) {
    f32x4 a = *(const f32x4*)p;
    f32x4 b = *(const f32x4*)(p + 4);
    s16x8 r;
    r[0] = (short)f2bf(a[0]); r[1] = (short)f2bf(a[1]);
    r[2] = (short)f2bf(a[2]); r[3] = (short)f2bf(a[3]);
    r[4] = (short)f2bf(b[0]); r[5] = (short)f2bf(b[1]);
    r[6] = (short)f2bf(b[2]); r[7] = (short)f2bf(b[3]);
    return r;
}

// ---- K0: blocks 0..95 cvt W_ih/W_hh -> bf16; block 96 folds Wc^T (bf16) + bc ----
__global__ __launch_bounds__(256) void prep_kernel(
    const float* __restrict__ W_pre, const float* __restrict__ b_pre,
    const float* __restrict__ W_gcn,
    const float* __restrict__ W_ih,  const float* __restrict__ W_hh,
    short* __restrict__ WcTB, float* __restrict__ bcw,
    short* __restrict__ WihB, short* __restrict__ WhhB)
{
    int b = blockIdx.x, t = threadIdx.x;
    if (b == 96) {
        for (int o = t; o < IND * GD; o += 256) {
            int k = o >> 6, d = o & 63;
            float s = 0.f;
            for (int m = 0; m < GD; ++m) s += W_pre[k * GD + m] * W_gcn[m * GD + d];
            WcTB[d * 32 + k] = (short)f2bf(s);
        }
        if (t < GD) {
            float s = 0.f;
            for (int m = 0; m < GD; ++m) s += b_pre[m] * W_gcn[m * GD + t];
            bcw[t] = s;
        }
    } else {
        int i = b * 256 + t;                  // 0..24575
        if (i < RD3 * GD) WihB[i] = (short)f2bf(W_ih[i]);
        else              WhhB[i - RD3 * GD] = (short)f2bf(W_hh[i - RD3 * GD]);
    }
}

// ---- fused: GCN (MFMA) + GRU (MFMA) + value head. 2 envs / block -----------------
__global__ __launch_bounds__(256, 3) void fused_kernel(
    const float* __restrict__ x,      // [4096][32][32]
    const void*  __restrict__ edge,   // [4096][2][256] int32 or int64
    const float* __restrict__ h0f,    // [N][64]
    const float* __restrict__ bcw,    // [64]  (b_pre @ W_gcn)
    const float* __restrict__ b_gcn,  // [64]
    const short* __restrict__ WcTB,   // [64][32] bf16 (Wc transposed)
    const short* __restrict__ WihB,   // [192][64] bf16
    const short* __restrict__ WhhB,   // [192][64] bf16
    const float* __restrict__ b_ih, const float* __restrict__ b_hh,
    const float* __restrict__ W_out,  // [2048]
    const float* __restrict__ b_out,
    float* __restrict__ value,        // [4096]
    float* __restrict__ hid_out)      // [N][64]
{
    __shared__ __align__(16) char smem[53008];
    float* sxT   = (float*)smem;                 // [2][32feat][36r]   9216B
    float* sAf   = (float*)(smem + 9216);        // [2][32c][36r] counts; later y
    float* s_hnew= (float*)smem;                 // [64][68] alias sxT+sAf (17408B)
    short* sAB   = (short*)(smem + 18432);       // [2][32c][40r] bf16  5120B
    float* saggF = (float*)(smem + 23552);       // [64][68]           17408B
    short* sh0B  = (short*)(smem + 40960);       // [64][72] bf16       9216B
    float* sdinv = (float*)(smem + 50176);       // [64]
    float* srsum = (float*)(smem + 50432);       // [64]
    int*   sdeg  = (int*)  (smem + 50688);       // [64]
    float* sbc   = (float*)(smem + 50944);       // [64]
    float* sbg   = (float*)(smem + 51200);       // [64]
    float* sbih  = (float*)(smem + 51456);       // [192]
    float* sbhh  = (float*)(smem + 52224);       // [192]
    float* sred  = (float*)(smem + 52992);       // [4]

    const int t = threadIdx.x;
    const int B = blockIdx.x;                    // env pair (2B, 2B+1)
    const int w = t >> 6, l = t & 63;
    const int col = l & 15, lg = l >> 4;
    const size_t nb = (size_t)B * 64;            // first node of block

    // ---- P0: issue global loads ----
    int pw = ((const int*)edge)[2 * t + 1];      // probe (first 2KB, safe both dtypes)
    f32x4 hr[4], xr[2];
    #pragma unroll
    for (int i = 0; i < 4; ++i) hr[i] = ((const f32x4*)(h0f + nb * GD))[t + i * 256];
    #pragma unroll
    for (int i = 0; i < 2; ++i) xr[i] = ((const f32x4*)(x + nb * IND))[t + i * 256];
    float bihv = 0.f, bhhv = 0.f, bcv = 0.f, bgv = 0.f;
    if (t < RD3) { bihv = b_ih[t]; bhhv = b_hh[t]; }
    if (t < GD)  { bcv = bcw[t]; bgv = b_gcn[t]; }

    // ---- P0b: dtype (per-wave ballot) + edge loads ----
    const bool is32 = __any(pw != 0);
    int er0, ec0, er1, ec1;
    if (is32) {
        const int* ep = (const int*)edge + (size_t)B * 1024;
        er0 = ep[t]; ec0 = ep[256 + t]; er1 = ep[512 + t]; ec1 = ep[768 + t];
    } else {
        const long long* ep = (const long long*)edge + (size_t)B * 1024;
        er0 = (int)ep[t]; ec0 = (int)ep[256 + t]; er1 = (int)ep[512 + t]; ec1 = (int)ep[768 + t];
    }

    // ---- P1: LDS init + staging ----
    #pragma unroll
    for (int i = 0; i < 3; ++i) {                // zero adjacency counts (2304 f)
        int o = t + i * 256;
        if (o < 576) ((f32x4*)sAf)[o] = (f32x4){0.f, 0.f, 0.f, 0.f};
    }
    if (t < 64) sdeg[t] = 1;                     // self loop
    if (t < RD3) { sbih[t] = bihv; sbhh[t] = bhhv; }
    if (t < GD)  { sbc[t] = bcv; sbg[t] = bgv; }
    #pragma unroll
    for (int i = 0; i < 2; ++i) {                // x -> transposed LDS (f32)
        int idx4 = t + i * 256;
        int e = idx4 >> 8, rr = (idx4 >> 3) & 31, f0 = (idx4 & 7) << 2;
        float* bp = sxT + e * 1152 + rr;
        bp[(f0 + 0) * 36] = xr[i][0]; bp[(f0 + 1) * 36] = xr[i][1];
        bp[(f0 + 2) * 36] = xr[i][2]; bp[(f0 + 3) * 36] = xr[i][3];
    }
    #pragma unroll
    for (int i = 0; i < 4; ++i) {                // h0 -> bf16 LDS
        int idx4 = t + i * 256;
        int node = idx4 >> 4, c0 = (idx4 & 15) << 2;
        s16x4 s4;
        s4[0] = (short)f2bf(hr[i][0]); s4[1] = (short)f2bf(hr[i][1]);
        s4[2] = (short)f2bf(hr[i][2]); s4[3] = (short)f2bf(hr[i][3]);
        *(s16x4*)(sh0B + node * 72 + c0) = s4;
    }
    __syncthreads();

    // ---- P2: adjacency + degree atomics ----
    atomicAdd(&sdeg[ec0], 1);
    atomicAdd(sAf + ec0 * 36 + er0, 1.0f);
    atomicAdd(&sdeg[32 + ec1], 1);
    atomicAdd(sAf + 1152 + ec1 * 36 + er1, 1.0f);
    __syncthreads();

    // ---- P3: dinv ----
    if (t < 64) sdinv[t] = rsqrtf((float)sdeg[t]);
    __syncthreads();

    // ---- P4: normalize -> bf16 A_hat + rowsum ----
    {
        int e = t >> 7, c = (t >> 2) & 31, r0 = (t & 3) * 8;
        float dc = sdinv[e * 32 + c];
        const float* cp = sAf + e * 1152 + c * 36 + r0;
        f32x4 c0 = *(const f32x4*)cp, c1 = *(const f32x4*)(cp + 4);
        float dot = 0.f;
        s16x8 vs;
        #pragma unroll
        for (int j = 0; j < 8; ++j) {
            float cnt = (j < 4) ? c0[j] : c1[j - 4];
            int r = r0 + j;
            float u = cnt * sdinv[e * 32 + r];
            dot += u;
            float v = u * dc;
            if (r == c) v += dc * dc;
            vs[j] = (short)f2bf(v);
        }
        dot += __shfl_xor(dot, 1);
        dot += __shfl_xor(dot, 2);
        if ((t & 3) == 0) srsum[e * 32 + c] = dc * dot + dc * dc;
        *(s16x8*)(sAB + e * 1280 + c * 40 + r0) = vs;
    }
    __syncthreads();

    // ---- P5/P6: y = A_hat @ x (MFMA), y -> syR (reuses counts region) ----
    const int e_w = w >> 1, m = (w & 1) * 16;
    float* syR = sAf;
    {
        s16x8 af = *(const s16x8*)(sAB + e_w * 1280 + (m + col) * 40 + lg * 8);
        f32x4 yac[2] = {};
        #pragma unroll
        for (int nt = 0; nt < 2; ++nt) {
            s16x8 bf = cvt8(sxT + e_w * 1152 + (nt * 16 + col) * 36 + lg * 8);
            yac[nt] = __builtin_amdgcn_mfma_f32_16x16x32_bf16(af, bf, yac[nt], 0, 0, 0);
        }
        // prefetch WcT B-fragments (global bf16, L2-hot)
        s16x8 wcf[4];
        #pragma unroll
        for (int nt = 0; nt < 4; ++nt)
            wcf[nt] = *(const s16x8*)(WcTB + (nt * 16 + col) * 32 + lg * 8);
        #pragma unroll
        for (int nt = 0; nt < 2; ++nt)
            #pragma unroll
            for (int r = 0; r < 4; ++r)
                syR[e_w * 1152 + (m + lg * 4 + r) * 36 + nt * 16 + col] = yac[nt][r];

        // ---- P7: agg = y @ Wc + rowsum*bc + b_gcn (same-wave LDS dependency) ----
        s16x8 afa = cvt8(syR + e_w * 1152 + (m + col) * 36 + lg * 8);
        f32x4 aac[4] = {};
        #pragma unroll
        for (int nt = 0; nt < 4; ++nt)
            aac[nt] = __builtin_amdgcn_mfma_f32_16x16x32_bf16(afa, wcf[nt], aac[nt], 0, 0, 0);
        #pragma unroll
        for (int nt = 0; nt < 4; ++nt)
            #pragma unroll
            for (int r = 0; r < 4; ++r) {
                int c = m + lg * 4 + r;
                int d = nt * 16 + col;
                float v = aac[nt][r] + srsum[e_w * 32 + c] * sbc[d] + sbg[d];
                saggF[(e_w * 32 + c) * 68 + d] = v;
            }
    }
    __syncthreads();

    // ---- P8: GRU MFMA (wave w owns gate dims [16w,16w+16)) ----
    f32x4 acc_i[3][4] = {}, acc_h[3][4] = {};
    #pragma unroll
    for (int kt = 0; kt < 2; ++kt) {
        s16x8 Ba[4], Bh[4];
        #pragma unroll
        for (int nt = 0; nt < 4; ++nt) {
            int node = nt * 16 + col;
            Ba[nt] = cvt8(saggF + node * 68 + kt * 32 + lg * 8);
            Bh[nt] = *(const s16x8*)(sh0B + node * 72 + kt * 32 + lg * 8);
        }
        #pragma unroll
        for (int g = 0; g < 3; ++g) {
            int wrow = g * 64 + 16 * w + col;
            s16x8 Ai = *(const s16x8*)(WihB + wrow * GD + kt * 32 + lg * 8);
            s16x8 Ah = *(const s16x8*)(WhhB + wrow * GD + kt * 32 + lg * 8);
            #pragma unroll
            for (int nt = 0; nt < 4; ++nt) {
                acc_i[g][nt] = __builtin_amdgcn_mfma_f32_16x16x32_bf16(Ai, Ba[nt], acc_i[g][nt], 0, 0, 0);
                acc_h[g][nt] = __builtin_amdgcn_mfma_f32_16x16x32_bf16(Ah, Bh[nt], acc_h[g][nt], 0, 0, 0);
            }
        }
    }

    // ---- P9: GRU epilogue -> s_hnew (aliases sxT/sAf; both dead since last barrier)
    const int dbase = 16 * w + 4 * lg;
    #pragma unroll
    for (int nt = 0; nt < 4; ++nt) {
        int node = nt * 16 + col;
        s16x4 hs = *(const s16x4*)(sh0B + node * 72 + dbase);
        #pragma unroll
        for (int r = 0; r < 4; ++r) {
            int d = dbase + r;
            float gir = acc_i[0][nt][r] + sbih[d];
            float giz = acc_i[1][nt][r] + sbih[64 + d];
            float gin = acc_i[2][nt][r] + sbih[128 + d];
            float ghr = acc_h[0][nt][r] + sbhh[d];
            float ghz = acc_h[1][nt][r] + sbhh[64 + d];
            float ghn = acc_h[2][nt][r] + sbhh[128 + d];
            float rr_ = 1.f / (1.f + __expf(-(gir + ghr)));
            float zz  = 1.f / (1.f + __expf(-(giz + ghz)));
            float e2  = __expf(2.f * (gin + rr_ * ghn));
            float nn  = 1.f - 2.f / (e2 + 1.f);
            float h0v = bf2f((unsigned short)hs[r]);
            s_hnew[node * 68 + d] = (1.f - zz) * nn + zz * h0v;
        }
    }
    __syncthreads();

    // ---- P10: flush hnew (coalesced) ----
    float* ho = hid_out + nb * GD;
    #pragma unroll
    for (int i = 0; i < 4; ++i) {
        int idx4 = t + i * 256;
        int row = idx4 >> 4, c4 = idx4 & 15;
        ((f32x4*)ho)[idx4] = *(const f32x4*)(s_hnew + row * 68 + c4 * 4);
    }

    // ---- P11: value head (half-block per env) ----
    float vsum = 0.f;
    {
        const int half = t >> 7, lt = t & 127;
        #pragma unroll
        for (int i = 0; i < 16; ++i) {
            int idx = lt + (i << 7);             // agent*64 + d
            int n = (idx >> 6) + half * 32;
            vsum += s_hnew[n * 68 + (idx & 63)] * W_out[idx];
        }
    }
    #pragma unroll
    for (int off = 32; off > 0; off >>= 1) vsum += __shfl_down(vsum, off, 64);
    if ((t & 63) == 0) sred[w] = vsum;
    __syncthreads();
    if (t == 0)   value[B * 2]     = sred[0] + sred[1] + b_out[0];
    if (t == 128) value[B * 2 + 1] = sred[2] + sred[3] + b_out[0];
}

// ---------------------------------------------------------------------------------
extern "C" void kernel_launch(void* const* d_in, const int* in_sizes, int n_in,
                              void* d_out, int out_size, void* d_ws, size_t ws_size,
                              hipStream_t stream)
{
    const float* x     = (const float*)d_in[0];
    const void*  edge  = d_in[1];
    const float* h0    = (const float*)d_in[2];
    const float* W_pre = (const float*)d_in[3];
    const float* b_pre = (const float*)d_in[4];
    const float* W_gcn = (const float*)d_in[5];
    const float* b_gcn = (const float*)d_in[6];
    const float* W_ih  = (const float*)d_in[7];
    const float* W_hh  = (const float*)d_in[8];
    const float* b_ih  = (const float*)d_in[9];
    const float* b_hh  = (const float*)d_in[10];
    const float* W_out = (const float*)d_in[11];
    const float* b_out = (const float*)d_in[12];

    float* value = (float*)d_out;
    float* hid   = (float*)d_out + NENV;

    short* WcTB = (short*)d_ws;                          // 2048 bf16  (4096B)
    float* bcw  = (float*)((char*)d_ws + 4096);          // 64 f32
    short* WihB = (short*)((char*)d_ws + 4608);          // 12288 bf16
    short* WhhB = WihB + RD3 * GD;                       // 12288 bf16

    prep_kernel<<<97, 256, 0, stream>>>(W_pre, b_pre, W_gcn, W_ih, W_hh,
                                        WcTB, bcw, WihB, WhhB);
    fused_kernel<<<NENV / 2, 256, 0, stream>>>(x, edge, h0, bcw, b_gcn, WcTB,
                                               WihB, WhhB, b_ih, b_hh,
                                               W_out, b_out, value, hid);
}

// Round 4
// 55.876 us; speedup vs baseline: 11.1807x; 1.1782x over previous
//
#include <hip/hip_runtime.h>

constexpr int NENV = 4096;
constexpr int GD   = 64;
constexpr int RD3  = 192;

typedef __attribute__((ext_vector_type(8))) short s16x8;
typedef __attribute__((ext_vector_type(4))) short s16x4;
typedef __attribute__((ext_vector_type(4))) float f32x4;

__device__ __forceinline__ unsigned short f2bf(float f) {
    unsigned u = __float_as_uint(f);
    u += 0x7FFFu + ((u >> 16) & 1u);
    return (unsigned short)(u >> 16);
}
__device__ __forceinline__ float bf2f(unsigned short u) {
    return __uint_as_float((unsigned)u << 16);
}
__device__ __forceinline__ float sigm(float v) { return 1.f / (1.f + __expf(-v)); }

// ---- K0: blocks 0..95 cvt W_ih/W_hh -> bf16; block 96 folds Wc^T (bf16) + bc ----
__global__ __launch_bounds__(256) void prep_kernel(
    const float* __restrict__ W_pre, const float* __restrict__ b_pre,
    const float* __restrict__ W_gcn,
    const float* __restrict__ W_ih,  const float* __restrict__ W_hh,
    short* __restrict__ WcTB, float* __restrict__ bcw,
    short* __restrict__ WihB, short* __restrict__ WhhB)
{
    int b = blockIdx.x, t = threadIdx.x;
    if (b == 96) {
        for (int o = t; o < 32 * GD; o += 256) {
            int k = o >> 6, d = o & 63;
            float s = 0.f;
            for (int m = 0; m < GD; ++m) s += W_pre[k * GD + m] * W_gcn[m * GD + d];
            WcTB[d * 32 + k] = (short)f2bf(s);
        }
        if (t < GD) {
            float s = 0.f;
            for (int m = 0; m < GD; ++m) s += b_pre[m] * W_gcn[m * GD + t];
            bcw[t] = s;
        }
    } else {
        int i = b * 256 + t;
        if (i < RD3 * GD) WihB[i] = (short)f2bf(W_ih[i]);
        else              WhhB[i - RD3 * GD] = (short)f2bf(W_hh[i - RD3 * GD]);
    }
}

// ---- fused: wave-per-env GCN (no barriers) + cooperative GRU. 4 envs/block ------
__global__ __launch_bounds__(256, 2) void fused_kernel(
    const float* __restrict__ x,      // [4096][32][32]
    const void*  __restrict__ edge,   // [4096][2][256] int32 or int64
    const float* __restrict__ h0f,    // [N][64]
    const float* __restrict__ bcw,    // [64]
    const float* __restrict__ b_gcn,  // [64]
    const short* __restrict__ WcTB,   // [64][32] bf16
    const short* __restrict__ WihB,   // [192][64] bf16
    const short* __restrict__ WhhB,   // [192][64] bf16
    const float* __restrict__ b_ih, const float* __restrict__ b_hh,
    const float* __restrict__ W_out,  // [2048]
    const float* __restrict__ b_out,
    float* __restrict__ value,        // [4096]
    float* __restrict__ hid_out)      // [N][64]
{
    // per-env region (17920B): [cnts f32[32][36] | yB bf16[32][40] | hnew f32[32][68]]
    //                          @0, [xT bf16[32][40]]@4608, [Ah bf16[32][40]]@7168,
    //                          [aggB bf16[32][64] swz]@9728, [h0B swz]@13824
    __shared__ __align__(16) char smem[72704];

    const int t   = threadIdx.x;
    const int w   = t >> 6, l = t & 63;
    const int col = l & 15, lg = l >> 4;
    const int B   = blockIdx.x;
    const int env = B * 4 + w;

    char*  eb    = smem + w * 17920;
    float* cnts  = (float*)eb;
    short* yB    = (short*)eb;
    short* xT    = (short*)(eb + 4608);
    short* Ah    = (short*)(eb + 7168);
    float* sdinv = (float*)(smem + 71680) + w * 32;
    float* srsum = (float*)(smem + 72192) + w * 32;

    // ================= P0: issue global loads =================
    const int4* pg = (const int4*)edge;          // dtype probe: first 2KB (shared)
    int4 pa = pg[l], pb = pg[l + 64];
    f32x4 xq[4], hq[8];
    #pragma unroll
    for (int i = 0; i < 4; ++i) xq[i] = ((const f32x4*)(x + (size_t)env * 1024))[l + i * 64];
    #pragma unroll
    for (int i = 0; i < 8; ++i) hq[i] = ((const f32x4*)(h0f + (size_t)env * 2048))[l + i * 64];

    const bool is32 = (__any((pa.y | pa.w | pb.y | pb.w) != 0) != 0);
    int rr_[4], cc_[4];
    if (is32) {
        const int4* e4 = (const int4*)((const char*)edge + (size_t)env * 2048);
        int4 r4 = e4[l], c4 = e4[64 + l];
        rr_[0] = r4.x; rr_[1] = r4.y; rr_[2] = r4.z; rr_[3] = r4.w;
        cc_[0] = c4.x; cc_[1] = c4.y; cc_[2] = c4.z; cc_[3] = c4.w;
    } else {
        const int4* e4 = (const int4*)((const char*)edge + (size_t)env * 4096);
        int4 ra = e4[2 * l], rb = e4[2 * l + 1];
        int4 ca = e4[128 + 2 * l], cb = e4[128 + 2 * l + 1];
        rr_[0] = ra.x; rr_[1] = ra.z; rr_[2] = rb.x; rr_[3] = rb.z;
        cc_[0] = ca.x; cc_[1] = ca.z; cc_[2] = cb.x; cc_[3] = cb.z;
    }

    // ================= P1: zero counts, stage xT / h0B (wave-local) ===============
    #pragma unroll
    for (int i = 0; i < 5; ++i) {                // 288 f32x4 = [32][36] f32
        int o = l + i * 64;
        if (o < 288) ((f32x4*)cnts)[o] = (f32x4){0.f, 0.f, 0.f, 0.f};
    }
    #pragma unroll
    for (int i = 0; i < 4; ++i) {                // x -> xT bf16 (transposed)
        int idx4 = l + i * 64;
        int n = idx4 >> 3, q = idx4 & 7;
        #pragma unroll
        for (int j = 0; j < 4; ++j) xT[(q * 4 + j) * 40 + n] = (short)f2bf(xq[i][j]);
    }
    char* h0b = eb + 13824;
    #pragma unroll
    for (int i = 0; i < 8; ++i) {                // h0 -> swizzled bf16 rows
        int idx4 = l + i * 64;
        int n = idx4 >> 4, q = idx4 & 15;
        s16x4 pk;
        pk[0] = (short)f2bf(hq[i][0]); pk[1] = (short)f2bf(hq[i][1]);
        pk[2] = (short)f2bf(hq[i][2]); pk[3] = (short)f2bf(hq[i][3]);
        *(s16x4*)(h0b + n * 128 + ((q * 8) ^ ((n & 7) << 4))) = pk;
    }

    // ================= P2: adjacency counts (wave-local atomics) ==================
    #pragma unroll
    for (int j = 0; j < 4; ++j) atomicAdd(cnts + cc_[j] * 36 + rr_[j], 1.0f);

    // ================= P3: degree + dinv (2 lanes per target) =====================
    const int c_  = l >> 1;
    const int r0_ = (l & 1) * 16;
    f32x4 cv[4];
    float s16 = 0.f;
    #pragma unroll
    for (int q = 0; q < 4; ++q) {
        cv[q] = *(const f32x4*)(cnts + c_ * 36 + r0_ + q * 4);
        s16 += cv[q][0] + cv[q][1] + cv[q][2] + cv[q][3];
    }
    float degs = s16 + __shfl_xor(s16, 1, 64);
    float dc = rsqrtf(1.0f + degs);
    if (!(l & 1)) sdinv[c_] = dc;

    // ================= P4: normalize -> Ah bf16, rowsum ===========================
    {
        f32x4 dv[4];
        #pragma unroll
        for (int q = 0; q < 4; ++q) dv[q] = *(const f32x4*)(sdinv + r0_ + q * 4);
        float dot = 0.f;
        s16x8 o0, o1;
        #pragma unroll
        for (int k = 0; k < 16; ++k) {
            float u = cv[k >> 2][k & 3] * dv[k >> 2][k & 3];
            dot += u;
            float v = u * dc;
            if (r0_ + k == c_) v += dc * dc;
            if (k < 8) o0[k] = (short)f2bf(v); else o1[k - 8] = (short)f2bf(v);
        }
        dot += __shfl_xor(dot, 1, 64);
        if (!(l & 1)) srsum[c_] = dc * dot + dc * dc;
        *(s16x8*)(Ah + c_ * 40 + r0_)     = o0;
        *(s16x8*)(Ah + c_ * 40 + r0_ + 8) = o1;
    }

    // ================= P5: yT = xT @ AhatT (4 MFMA), write yB[node][feat] =========
    {
        s16x8 Ax0 = *(const s16x8*)(xT + col * 40 + lg * 8);
        s16x8 Ax1 = *(const s16x8*)(xT + (16 + col) * 40 + lg * 8);
        s16x8 Bh0 = *(const s16x8*)(Ah + col * 40 + lg * 8);
        s16x8 Bh1 = *(const s16x8*)(Ah + (16 + col) * 40 + lg * 8);
        f32x4 y00 = {}, y01 = {}, y10 = {}, y11 = {};
        y00 = __builtin_amdgcn_mfma_f32_16x16x32_bf16(Ax0, Bh0, y00, 0, 0, 0);
        y01 = __builtin_amdgcn_mfma_f32_16x16x32_bf16(Ax0, Bh1, y01, 0, 0, 0);
        y10 = __builtin_amdgcn_mfma_f32_16x16x32_bf16(Ax1, Bh0, y10, 0, 0, 0);
        y11 = __builtin_amdgcn_mfma_f32_16x16x32_bf16(Ax1, Bh1, y11, 0, 0, 0);
        // acc (f,d): node = d*16+col, feats f*16+lg*4.. -> b64 writes
        #pragma unroll
        for (int f = 0; f < 2; ++f)
            #pragma unroll
            for (int d = 0; d < 2; ++d) {
                f32x4 a = (f == 0) ? (d == 0 ? y00 : y01) : (d == 0 ? y10 : y11);
                s16x4 pk;
                pk[0] = (short)f2bf(a[0]); pk[1] = (short)f2bf(a[1]);
                pk[2] = (short)f2bf(a[2]); pk[3] = (short)f2bf(a[3]);
                *(s16x4*)(yB + (d * 16 + col) * 40 + f * 16 + lg * 4) = pk;
            }
    }

    // ================= P6: aggT = WcT @ yT (8 MFMA) + epilogue -> aggB swz ========
    {
        s16x8 Aw[4];
        #pragma unroll
        for (int a = 0; a < 4; ++a)
            Aw[a] = *(const s16x8*)(WcTB + (a * 16 + col) * 32 + lg * 8);
        s16x8 By0 = *(const s16x8*)(yB + col * 40 + lg * 8);
        s16x8 By1 = *(const s16x8*)(yB + (16 + col) * 40 + lg * 8);
        float rs0 = srsum[col], rs1 = srsum[16 + col];
        char* ab = eb + 9728;
        #pragma unroll
        for (int a = 0; a < 4; ++a) {
            f32x4 g0 = {}, g1 = {};
            g0 = __builtin_amdgcn_mfma_f32_16x16x32_bf16(Aw[a], By0, g0, 0, 0, 0);
            g1 = __builtin_amdgcn_mfma_f32_16x16x32_bf16(Aw[a], By1, g1, 0, 0, 0);
            f32x4 bc4 = *(const f32x4*)(bcw + a * 16 + lg * 4);
            f32x4 bg4 = *(const f32x4*)(b_gcn + a * 16 + lg * 4);
            #pragma unroll
            for (int n = 0; n < 2; ++n) {
                f32x4 g = n ? g1 : g0;
                float rs = n ? rs1 : rs0;
                int node = n * 16 + col;
                s16x4 pk;
                #pragma unroll
                for (int r = 0; r < 4; ++r) pk[r] = (short)f2bf(g[r] + rs * bc4[r] + bg4[r]);
                *(s16x4*)(ab + node * 128 + (((a * 32 + lg * 8)) ^ ((node & 7) << 4))) = pk;
            }
        }
    }
    __syncthreads();   // ---- barrier 1: all envs' aggB/h0B ready ----

    // ================= P7: GRU — wave w owns d-slice [16w,16w+16) ================
    const int db = 16 * w + lg * 4;
    f32x4 accr[8] = {}, accz[8] = {}, accin[8] = {}, acchn[8] = {};
    #pragma unroll
    for (int kt = 0; kt < 2; ++kt) {
        const int wr = (16 * w + col) * 64 + kt * 32 + lg * 8;
        s16x8 Ari = *(const s16x8*)(WihB + wr);
        s16x8 Azi = *(const s16x8*)(WihB + 64 * 64 + wr);
        s16x8 Ani = *(const s16x8*)(WihB + 128 * 64 + wr);
        s16x8 Arh = *(const s16x8*)(WhhB + wr);
        s16x8 Azh = *(const s16x8*)(WhhB + 64 * 64 + wr);
        s16x8 Anh = *(const s16x8*)(WhhB + 128 * 64 + wr);
        #pragma unroll
        for (int nt = 0; nt < 8; ++nt) {
            char* ab = smem + (nt >> 1) * 17920 + 9728;
            char* hb = smem + (nt >> 1) * 17920 + 13824;
            int node = (nt & 1) * 16 + col;
            int off = node * 128 + ((kt * 64 + lg * 16) ^ ((node & 7) << 4));
            s16x8 Ba = *(const s16x8*)(ab + off);
            s16x8 Bh = *(const s16x8*)(hb + off);
            accr[nt]  = __builtin_amdgcn_mfma_f32_16x16x32_bf16(Ari, Ba, accr[nt], 0, 0, 0);
            accr[nt]  = __builtin_amdgcn_mfma_f32_16x16x32_bf16(Arh, Bh, accr[nt], 0, 0, 0);
            accz[nt]  = __builtin_amdgcn_mfma_f32_16x16x32_bf16(Azi, Ba, accz[nt], 0, 0, 0);
            accz[nt]  = __builtin_amdgcn_mfma_f32_16x16x32_bf16(Azh, Bh, accz[nt], 0, 0, 0);
            accin[nt] = __builtin_amdgcn_mfma_f32_16x16x32_bf16(Ani, Ba, accin[nt], 0, 0, 0);
            acchn[nt] = __builtin_amdgcn_mfma_f32_16x16x32_bf16(Anh, Bh, acchn[nt], 0, 0, 0);
        }
    }
    {
        f32x4 br  = *(const f32x4*)(b_ih + db);
        f32x4 bz  = *(const f32x4*)(b_ih + 64 + db);
        f32x4 bin = *(const f32x4*)(b_ih + 128 + db);
        f32x4 bhn = *(const f32x4*)(b_hh + 128 + db);
        {
            f32x4 t1 = *(const f32x4*)(b_hh + db);
            f32x4 t2 = *(const f32x4*)(b_hh + 64 + db);
            br += t1; bz += t2;
        }
        #pragma unroll
        for (int nt = 0; nt < 8; ++nt) {
            char* hb = smem + (nt >> 1) * 17920 + 13824;
            float* hnew = (float*)(smem + (nt >> 1) * 17920);
            int node = (nt & 1) * 16 + col;
            s16x4 h04 = *(const s16x4*)(hb + node * 128 + ((32 * w + 8 * lg) ^ ((node & 7) << 4)));
            f32x4 out;
            #pragma unroll
            for (int r = 0; r < 4; ++r) {
                float rg = sigm(accr[nt][r] + br[r]);
                float zg = sigm(accz[nt][r] + bz[r]);
                float e2 = __expf(2.f * (accin[nt][r] + bin[r] + rg * (acchn[nt][r] + bhn[r])));
                float ng = 1.f - 2.f / (e2 + 1.f);
                out[r] = (1.f - zg) * ng + zg * bf2f((unsigned short)h04[r]);
            }
            *(f32x4*)(hnew + node * 68 + db) = out;
        }
    }
    __syncthreads();   // ---- barrier 2: hnew complete ----

    // ================= P8: flush + value head (wave w -> env w) ===================
    {
        float* hn = (float*)(smem + w * 17920);
        float* ho = hid_out + (size_t)env * 2048;
        float vsum = 0.f;
        #pragma unroll
        for (int i = 0; i < 8; ++i) {
            int idx4 = l + i * 64;
            int row = idx4 >> 4, q = idx4 & 15;
            f32x4 hv = *(const f32x4*)(hn + row * 68 + q * 4);
            ((f32x4*)ho)[idx4] = hv;
            f32x4 wv = ((const f32x4*)W_out)[idx4];
            vsum += hv[0] * wv[0] + hv[1] * wv[1] + hv[2] * wv[2] + hv[3] * wv[3];
        }
        #pragma unroll
        for (int off = 32; off > 0; off >>= 1) vsum += __shfl_down(vsum, off, 64);
        if (l == 0) value[env] = vsum + b_out[0];
    }
}

// ---------------------------------------------------------------------------------
extern "C" void kernel_launch(void* const* d_in, const int* in_sizes, int n_in,
                              void* d_out, int out_size, void* d_ws, size_t ws_size,
                              hipStream_t stream)
{
    const float* x     = (const float*)d_in[0];
    const void*  edge  = d_in[1];
    const float* h0    = (const float*)d_in[2];
    const float* W_pre = (const float*)d_in[3];
    const float* b_pre = (const float*)d_in[4];
    const float* W_gcn = (const float*)d_in[5];
    const float* b_gcn = (const float*)d_in[6];
    const float* W_ih  = (const float*)d_in[7];
    const float* W_hh  = (const float*)d_in[8];
    const float* b_ih  = (const float*)d_in[9];
    const float* b_hh  = (const float*)d_in[10];
    const float* W_out = (const float*)d_in[11];
    const float* b_out = (const float*)d_in[12];

    float* value = (float*)d_out;
    float* hid   = (float*)d_out + NENV;

    short* WcTB = (short*)d_ws;                          // 2048 bf16
    float* bcw  = (float*)((char*)d_ws + 4096);          // 64 f32
    short* WihB = (short*)((char*)d_ws + 4608);          // 12288 bf16
    short* WhhB = WihB + RD3 * GD;                       // 12288 bf16

    prep_kernel<<<97, 256, 0, stream>>>(W_pre, b_pre, W_gcn, W_ih, W_hh,
                                        WcTB, bcw, WihB, WhhB);
    fused_kernel<<<NENV / 4, 256, 0, stream>>>(x, edge, h0, bcw, b_gcn, WcTB,
                                               WihB, WhhB, b_ih, b_hh,
                                               W_out, b_out, value, hid);
}